// Round 4
// baseline (338.562 us; speedup 1.0000x reference)
//
#include <hip/hip_runtime.h>

constexpr int IN_F = 128;
constexpr int NH   = 4;    // heads
constexpr int ND   = 32;   // dim per head
constexpr int HD   = 128;  // NH*ND
constexpr float NEG_SLOPE = 0.2f;

__device__ inline unsigned bf16b(float f) {  // f32 -> bf16 bits, RNE
  unsigned u = __float_as_uint(f);
  return (u + 0x7FFFu + ((u >> 16) & 1u)) >> 16;
}
__device__ inline unsigned packpair(float lo, float hi) {
  return bf16b(lo) | (bf16b(hi) << 16);
}

// ---- Kernel A: ft = feat @ W, fused el/er epilogue, bf16-pair ft output ----
// ftb2[node*64 + c] = (bf16(ft[node][c]), bf16(ft[node][c+64])) packed in uint.
__global__ __launch_bounds__(256) void k_gemm(
    const float* __restrict__ feat, const float* __restrict__ W,
    const float* __restrict__ attn_l, const float* __restrict__ attn_r,
    unsigned* __restrict__ ftb2, float* __restrict__ el, float* __restrict__ er,
    int n) {
  __shared__ float sW[IN_F * HD];  // 64 KiB
  for (int i = threadIdx.x; i < IN_F * HD; i += 256) sW[i] = W[i];
  __syncthreads();
  const int t  = threadIdx.x;
  const int rg = t >> 5;             // 0..7 row group (4 rows each)
  const int c0 = (t & 31) << 2;      // 4 output cols
  const int h  = c0 >> 5;            // head of these cols
  const int hc = c0 & 31;            // col within head
  const float4 al = *(const float4*)(attn_l + h * ND + hc);
  const float4 ar = *(const float4*)(attn_r + h * ND + hc);

  for (int base = blockIdx.x * 32; base < n; base += gridDim.x * 32) {
    const int r0 = base + rg * 4;
    const float* rp0 = feat + (size_t)min(r0 + 0, n - 1) * IN_F;
    const float* rp1 = feat + (size_t)min(r0 + 1, n - 1) * IN_F;
    const float* rp2 = feat + (size_t)min(r0 + 2, n - 1) * IN_F;
    const float* rp3 = feat + (size_t)min(r0 + 3, n - 1) * IN_F;
    float acc[4][4];
#pragma unroll
    for (int i = 0; i < 4; ++i)
#pragma unroll
      for (int j = 0; j < 4; ++j) acc[i][j] = 0.f;

#pragma unroll 4
    for (int k4 = 0; k4 < IN_F / 4; ++k4) {
      const float4 w0 = *(const float4*)&sW[(k4 * 4 + 0) * HD + c0];
      const float4 w1 = *(const float4*)&sW[(k4 * 4 + 1) * HD + c0];
      const float4 w2 = *(const float4*)&sW[(k4 * 4 + 2) * HD + c0];
      const float4 w3 = *(const float4*)&sW[(k4 * 4 + 3) * HD + c0];
      const float4 f0 = *(const float4*)(rp0 + k4 * 4);
      const float4 f1 = *(const float4*)(rp1 + k4 * 4);
      const float4 f2 = *(const float4*)(rp2 + k4 * 4);
      const float4 f3 = *(const float4*)(rp3 + k4 * 4);
#define ROWFMA(rr, fv)                                              \
      acc[rr][0] += fv.x * w0.x + fv.y * w1.x + fv.z * w2.x + fv.w * w3.x; \
      acc[rr][1] += fv.x * w0.y + fv.y * w1.y + fv.z * w2.y + fv.w * w3.y; \
      acc[rr][2] += fv.x * w0.z + fv.y * w1.z + fv.z * w2.z + fv.w * w3.z; \
      acc[rr][3] += fv.x * w0.w + fv.y * w1.w + fv.z * w2.w + fv.w * w3.w;
      ROWFMA(0, f0) ROWFMA(1, f1) ROWFMA(2, f2) ROWFMA(3, f3)
#undef ROWFMA
    }

    // Epilogue: el/er via 8-lane shfl reduction; bf16 pair-pack via lane^16.
#pragma unroll
    for (int rr = 0; rr < 4; ++rr) {
      const int r = r0 + rr;
      float pl = acc[rr][0] * al.x + acc[rr][1] * al.y + acc[rr][2] * al.z + acc[rr][3] * al.w;
      float pr = acc[rr][0] * ar.x + acc[rr][1] * ar.y + acc[rr][2] * ar.z + acc[rr][3] * ar.w;
      pl += __shfl_xor(pl, 1); pl += __shfl_xor(pl, 2); pl += __shfl_xor(pl, 4);
      pr += __shfl_xor(pr, 1); pr += __shfl_xor(pr, 2); pr += __shfl_xor(pr, 4);
      if ((t & 7) == 0 && r < n) {
        el[r * NH + h] = pl;
        er[r * NH + h] = pr;
      }
      // partner lane holds cols c0^64
      const float p0 = __shfl_xor(acc[rr][0], 16);
      const float p1 = __shfl_xor(acc[rr][1], 16);
      const float p2 = __shfl_xor(acc[rr][2], 16);
      const float p3 = __shfl_xor(acc[rr][3], 16);
      if ((t & 16) == 0 && r < n) {  // low half (c0 < 64) stores the pairs
        uint4 pk;
        pk.x = packpair(acc[rr][0], p0);
        pk.y = packpair(acc[rr][1], p1);
        pk.z = packpair(acc[rr][2], p2);
        pk.w = packpair(acc[rr][3], p3);
        *(uint4*)&ftb2[(size_t)r * 64 + c0] = pk;
      }
    }
  }
}

// ---- Kernel R: rank[e] = atomicAdd(deg[dst[e]],1), 4 edges/thread ---------
__global__ __launch_bounds__(256) void k_rank(
    const int* __restrict__ dst, int* __restrict__ deg, int* __restrict__ rank,
    int ne) {
  const int e4 = (blockIdx.x * 256 + threadIdx.x) * 4;
  if (e4 + 4 <= ne) {
    const int4 d = *(const int4*)(dst + e4);
    int4 r;
    r.x = atomicAdd(deg + d.x, 1);
    r.y = atomicAdd(deg + d.y, 1);
    r.z = atomicAdd(deg + d.z, 1);
    r.w = atomicAdd(deg + d.w, 1);
    *(int4*)(rank + e4) = r;
  } else {
    for (int e = e4; e < ne; ++e) rank[e] = atomicAdd(deg + dst[e], 1);
  }
}

// ---------------- Scan: exclusive prefix over deg (3 kernels) --------------
__global__ __launch_bounds__(256) void k_scan1(
    const int* __restrict__ deg, int* __restrict__ pexcl,
    int* __restrict__ bsum, int n) {
  const int t = threadIdx.x;
  const int base = blockIdx.x * 1024 + t * 4;
  int v0 = base + 0 < n ? deg[base + 0] : 0;
  int v1 = base + 1 < n ? deg[base + 1] : 0;
  int v2 = base + 2 < n ? deg[base + 2] : 0;
  int v3 = base + 3 < n ? deg[base + 3] : 0;
  const int s = v0 + v1 + v2 + v3;
  const int lane = t & 63, w = t >> 6;
  int x = s;
#pragma unroll
  for (int off = 1; off < 64; off <<= 1) {
    int y = __shfl_up(x, off);
    if (lane >= off) x += y;
  }
  __shared__ int ws[4];
  if (lane == 63) ws[w] = x;
  __syncthreads();
  int woff = 0;
  for (int i = 0; i < w; ++i) woff += ws[i];
  int run = woff + x - s;
  if (base + 0 < n) { pexcl[base + 0] = run; run += v0; }
  if (base + 1 < n) { pexcl[base + 1] = run; run += v1; }
  if (base + 2 < n) { pexcl[base + 2] = run; run += v2; }
  if (base + 3 < n) { pexcl[base + 3] = run; run += v3; }
  if (t == 0) bsum[blockIdx.x] = ws[0] + ws[1] + ws[2] + ws[3];
}

__global__ __launch_bounds__(256) void k_scan2(
    const int* __restrict__ bsum, int* __restrict__ boff, int B) {
  const int t = threadIdx.x;
  const int s = t < B ? bsum[t] : 0;
  const int lane = t & 63, w = t >> 6;
  int x = s;
#pragma unroll
  for (int off = 1; off < 64; off <<= 1) {
    int y = __shfl_up(x, off);
    if (lane >= off) x += y;
  }
  __shared__ int ws[4];
  if (lane == 63) ws[w] = x;
  __syncthreads();
  int woff = 0;
  for (int i = 0; i < w; ++i) woff += ws[i];
  if (t < B) boff[t] = woff + x - s;
}

__global__ __launch_bounds__(256) void k_scan3(
    const int* __restrict__ pexcl, const int* __restrict__ boff,
    int* __restrict__ offsets, int n, int ne) {
  const int i = blockIdx.x * 256 + threadIdx.x;
  if (i < n) offsets[i] = pexcl[i] + boff[i >> 10];
  if (i == 0) offsets[n] = ne;
}

// ------ Kernel S: scatter src into dst-CSR (atomic-free, 4 edges/thread) ---
__global__ __launch_bounds__(256) void k_scatter(
    const int* __restrict__ src, const int* __restrict__ dst,
    const int* __restrict__ rank, const int* __restrict__ offsets,
    int* __restrict__ src_sorted, int ne) {
  const int e4 = (blockIdx.x * 256 + threadIdx.x) * 4;
  if (e4 + 4 <= ne) {
    const int4 s = *(const int4*)(src + e4);
    const int4 d = *(const int4*)(dst + e4);
    const int4 r = *(const int4*)(rank + e4);
    src_sorted[offsets[d.x] + r.x] = s.x;
    src_sorted[offsets[d.y] + r.y] = s.y;
    src_sorted[offsets[d.z] + r.z] = s.z;
    src_sorted[offsets[d.w] + r.w] = s.w;
  } else {
    for (int e = e4; e < ne; ++e)
      src_sorted[offsets[dst[e]] + rank[e]] = src[e];
  }
}

// ------ Kernel D: fused softmax + aggregation, one wave per dst node -------
__global__ __launch_bounds__(256) void k_aggr(
    const int* __restrict__ offsets, const int* __restrict__ src_sorted,
    const float* __restrict__ el, const float* __restrict__ er,
    const unsigned* __restrict__ ftb2, float* __restrict__ out, int n) {
  const int wid = (blockIdx.x * 256 + threadIdx.x) >> 6;
  if (wid >= n) return;
  const int lane = threadIdx.x & 63;
  const int hsel = lane >> 5;  // head of elem 'lane'; elem lane+64 -> 2+hsel
  const int start = offsets[wid], end = offsets[wid + 1];
  const float er0 = er[wid * NH + hsel];
  const float er1 = er[wid * NH + 2 + hsel];
  float acc0 = 0.f, acc1 = 0.f, den0 = 0.f, den1 = 0.f;

  int i = start;
  for (; i + 2 <= end; i += 2) {
    const int sA = src_sorted[i], sB = src_sorted[i + 1];
    float eA0 = el[sA * NH + hsel] + er0;
    float eA1 = el[sA * NH + 2 + hsel] + er1;
    float eB0 = el[sB * NH + hsel] + er0;
    float eB1 = el[sB * NH + 2 + hsel] + er1;
    eA0 = eA0 > 0.f ? eA0 : NEG_SLOPE * eA0;
    eA1 = eA1 > 0.f ? eA1 : NEG_SLOPE * eA1;
    eB0 = eB0 > 0.f ? eB0 : NEG_SLOPE * eB0;
    eB1 = eB1 > 0.f ? eB1 : NEG_SLOPE * eB1;
    const float pA0 = __expf(eA0), pA1 = __expf(eA1);
    const float pB0 = __expf(eB0), pB1 = __expf(eB1);
    const unsigned vA = ftb2[(size_t)sA * 64 + lane];
    const unsigned vB = ftb2[(size_t)sB * 64 + lane];
    const float fA0 = __uint_as_float(vA << 16);
    const float fA1 = __uint_as_float(vA & 0xFFFF0000u);
    const float fB0 = __uint_as_float(vB << 16);
    const float fB1 = __uint_as_float(vB & 0xFFFF0000u);
    acc0 += fA0 * pA0 + fB0 * pB0;
    acc1 += fA1 * pA1 + fB1 * pB1;
    den0 += pA0 + pB0;
    den1 += pA1 + pB1;
  }
  if (i < end) {
    const int s = src_sorted[i];
    float e0 = el[s * NH + hsel] + er0;
    float e1 = el[s * NH + 2 + hsel] + er1;
    e0 = e0 > 0.f ? e0 : NEG_SLOPE * e0;
    e1 = e1 > 0.f ? e1 : NEG_SLOPE * e1;
    const float p0 = __expf(e0), p1 = __expf(e1);
    const unsigned v = ftb2[(size_t)s * 64 + lane];
    acc0 += __uint_as_float(v << 16) * p0;
    acc1 += __uint_as_float(v & 0xFFFF0000u) * p1;
    den0 += p0;
    den1 += p1;
  }
  den0 = den0 > 0.f ? den0 : 1.f;  // isolated-node guard (matches reference)
  den1 = den1 > 0.f ? den1 : 1.f;
  float* orow = out + (size_t)wid * HD;
  orow[lane] = acc0 / den0;
  orow[64 + lane] = acc1 / den1;
}

extern "C" void kernel_launch(void* const* d_in, const int* in_sizes, int n_in,
                              void* d_out, int out_size, void* d_ws, size_t ws_size,
                              hipStream_t stream) {
  const float* feat   = (const float*)d_in[0];
  const float* W      = (const float*)d_in[1];
  const float* attn_l = (const float*)d_in[2];
  const float* attn_r = (const float*)d_in[3];
  const int*   src    = (const int*)d_in[4];
  const int*   dst    = (const int*)d_in[5];
  const int n  = in_sizes[0] / IN_F;
  const int ne = in_sizes[4];
  float* out = (float*)d_out;

  // workspace layout (16B-aligned blocks first)
  char* wp = (char*)d_ws;
  unsigned* ftb2    = (unsigned*)wp; wp += (size_t)n * 64 * 4;   // 25.6 MB
  float* el         = (float*)wp;    wp += (size_t)n * NH * 4;
  float* er         = (float*)wp;    wp += (size_t)n * NH * 4;
  int*   rank       = (int*)wp;      wp += (size_t)ne * 4;
  int*   src_sorted = (int*)wp;      wp += (size_t)ne * 4;
  int*   deg        = (int*)wp;      wp += (size_t)n * 4;
  int*   pexcl      = (int*)wp;      wp += (size_t)n * 4;
  int*   offsets    = (int*)wp;      wp += (size_t)(n + 1) * 4;
  int*   bsum       = (int*)wp;      wp += 256 * 4;
  int*   boff       = (int*)wp;      wp += 256 * 4;

  hipMemsetAsync(deg, 0, (size_t)n * 4, stream);

  const int B = (n + 1023) / 1024;
  k_gemm<<<1024, 256, 0, stream>>>(feat, W, attn_l, attn_r, ftb2, el, er, n);
  k_rank<<<(ne + 1023) / 1024, 256, 0, stream>>>(dst, deg, rank, ne);
  k_scan1<<<B, 256, 0, stream>>>(deg, pexcl, bsum, n);
  k_scan2<<<1, 256, 0, stream>>>(bsum, boff, B);
  k_scan3<<<(n + 255) / 256, 256, 0, stream>>>(pexcl, boff, offsets, n, ne);
  k_scatter<<<(ne + 1023) / 1024, 256, 0, stream>>>(src, dst, rank, offsets,
                                                    src_sorted, ne);
  k_aggr<<<(n + 3) / 4, 256, 0, stream>>>(offsets, src_sorted, el, er, ftb2, out, n);
}

// Round 5
// 284.505 us; speedup vs baseline: 1.1900x; 1.1900x over previous
//
#include <hip/hip_runtime.h>

constexpr int IN_F = 128;
constexpr int NH   = 4;    // heads
constexpr int ND   = 32;   // dim per head
constexpr int HD   = 128;  // NH*ND
constexpr float NEG_SLOPE = 0.2f;

using short8 = __attribute__((ext_vector_type(8))) short;
using f32x4  = __attribute__((ext_vector_type(4))) float;

__device__ inline unsigned bf16b(float f) {  // f32 -> bf16 bits, RNE
  unsigned u = __float_as_uint(f);
  return (u + 0x7FFFu + ((u >> 16) & 1u)) >> 16;
}

// ---- Kernel A: MFMA GEMM  ft(bf16-pair-packed) + el/er fused as extra cols -
// LDS sB: bf16 Wt_ext[144][128]  (row = output col c, k along row),
//   rows 0..127   : W^T (Wt[c][k] = W[k][c])
//   rows 128..135 : (W @ [AL|AR])^T  -> el (h=0..3), er (h=0..3)
//   rows 136..143 : zero
// 16B slots XOR-swizzled within each row: slot_stored = slot ^ (row&7).
__global__ __launch_bounds__(256) void k_gemm(
    const float* __restrict__ feat, const float* __restrict__ W,
    const float* __restrict__ attn_l, const float* __restrict__ attn_r,
    unsigned* __restrict__ ftb2, float* __restrict__ el, float* __restrict__ er,
    int n) {
  __shared__ unsigned sB[144 * 64];  // 36864 B (uint = 2 bf16)
  const int t = threadIdx.x;

  // ---- per-block prep: build swizzled bf16 W^T (+ el/er cols) in LDS ----
  for (int item = t; item < 144 * 16; item += 256) {
    const int r = item >> 4, s = item & 15;  // ext output-col r, 16B k-slot s
    const int k0 = s * 8;
    unsigned pk[4];
    if (r < HD) {
#pragma unroll
      for (int j2 = 0; j2 < 4; ++j2) {
        const unsigned lo = bf16b(W[(size_t)(k0 + 2 * j2) * HD + r]);
        const unsigned hi = bf16b(W[(size_t)(k0 + 2 * j2 + 1) * HD + r]);
        pk[j2] = lo | (hi << 16);
      }
    } else if (r < HD + 8) {
      const int j8 = r - HD;  // 0..3 -> el head, 4..7 -> er head
      const int h = j8 & 3;
      const float* av = (j8 < 4 ? attn_l : attn_r) + h * ND;
      float sums[8];
#pragma unroll
      for (int j = 0; j < 8; ++j) {
        const float4* wv = (const float4*)&W[(size_t)(k0 + j) * HD + h * ND];
        const float4* a4 = (const float4*)av;
        float sum = 0.f;
#pragma unroll
        for (int c4 = 0; c4 < ND / 4; ++c4) {
          const float4 w = wv[c4], a = a4[c4];
          sum += w.x * a.x + w.y * a.y + w.z * a.z + w.w * a.w;
        }
        sums[j] = sum;
      }
#pragma unroll
      for (int j2 = 0; j2 < 4; ++j2)
        pk[j2] = bf16b(sums[2 * j2]) | (bf16b(sums[2 * j2 + 1]) << 16);
    } else {
      pk[0] = pk[1] = pk[2] = pk[3] = 0;
    }
    unsigned* dp = &sB[r * 64 + ((s ^ (r & 7)) << 2)];
    *(uint4*)dp = make_uint4(pk[0], pk[1], pk[2], pk[3]);
  }
  __syncthreads();

  // ---- main MFMA loop: wave handles 2 strips of 16 rows (32 rows) ----
  const int lane = t & 63;
  const int wv   = t >> 6;                 // wave 0..3
  const int r0   = blockIdx.x * 128 + wv * 32;
  if (r0 >= n) return;
  const int lrow = lane & 15;              // A row / B col within tile
  const int lk   = lane >> 4;              // k-chunk 0..3

  f32x4 acc[2][9];
#pragma unroll
  for (int st = 0; st < 2; ++st)
#pragma unroll
    for (int ct = 0; ct < 9; ++ct) acc[st][ct] = (f32x4)0.f;

#pragma unroll
  for (int ks = 0; ks < 4; ++ks) {
    short8 b[9];
#pragma unroll
    for (int ct = 0; ct < 9; ++ct) {
      const int row = ct * 16 + lrow;
      const int slot = ks * 4 + lk;
      b[ct] = *(const short8*)&sB[row * 64 + ((slot ^ (row & 7)) << 2)];
    }
#pragma unroll
    for (int st = 0; st < 2; ++st) {
      int arow = r0 + st * 16 + lrow;
      arow = arow < n ? arow : n - 1;
      const float* ap = feat + (size_t)arow * IN_F + ks * 32 + lk * 8;
      const float4 f0 = *(const float4*)ap;
      const float4 f1 = *(const float4*)(ap + 4);
      short8 a;
      a[0] = (short)bf16b(f0.x); a[1] = (short)bf16b(f0.y);
      a[2] = (short)bf16b(f0.z); a[3] = (short)bf16b(f0.w);
      a[4] = (short)bf16b(f1.x); a[5] = (short)bf16b(f1.y);
      a[6] = (short)bf16b(f1.z); a[7] = (short)bf16b(f1.w);
#pragma unroll
      for (int ct = 0; ct < 9; ++ct)
        acc[st][ct] = __builtin_amdgcn_mfma_f32_16x16x32_bf16(a, b[ct], acc[st][ct], 0, 0, 0);
    }
  }

  // ---- epilogue: C/D layout col=lane&15, row=(lane>>4)*4+reg ----
#pragma unroll
  for (int st = 0; st < 2; ++st) {
#pragma unroll
    for (int i = 0; i < 4; ++i) {
      const int r = r0 + st * 16 + lk * 4 + i;
      if (r >= n) continue;
#pragma unroll
      for (int ct = 0; ct < 4; ++ct) {
        const unsigned pk = bf16b(acc[st][ct][i]) | (bf16b(acc[st][ct + 4][i]) << 16);
        ftb2[(size_t)r * 64 + ct * 16 + lrow] = pk;
      }
      if (lrow < 4)      el[r * NH + lrow]     = acc[st][8][i];
      else if (lrow < 8) er[r * NH + lrow - 4] = acc[st][8][i];
    }
  }
}

// ---- Kernel R: rank[e] = atomicAdd(deg[dst[e]],1), 4 edges/thread ---------
__global__ __launch_bounds__(256) void k_rank(
    const int* __restrict__ dst, int* __restrict__ deg, int* __restrict__ rank,
    int ne) {
  const int e4 = (blockIdx.x * 256 + threadIdx.x) * 4;
  if (e4 + 4 <= ne) {
    const int4 d = *(const int4*)(dst + e4);
    int4 r;
    r.x = atomicAdd(deg + d.x, 1);
    r.y = atomicAdd(deg + d.y, 1);
    r.z = atomicAdd(deg + d.z, 1);
    r.w = atomicAdd(deg + d.w, 1);
    *(int4*)(rank + e4) = r;
  } else {
    for (int e = e4; e < ne; ++e) rank[e] = atomicAdd(deg + dst[e], 1);
  }
}

// ---------------- Scan: exclusive prefix over deg (3 kernels) --------------
__global__ __launch_bounds__(256) void k_scan1(
    const int* __restrict__ deg, int* __restrict__ pexcl,
    int* __restrict__ bsum, int n) {
  const int t = threadIdx.x;
  const int base = blockIdx.x * 1024 + t * 4;
  int v0 = base + 0 < n ? deg[base + 0] : 0;
  int v1 = base + 1 < n ? deg[base + 1] : 0;
  int v2 = base + 2 < n ? deg[base + 2] : 0;
  int v3 = base + 3 < n ? deg[base + 3] : 0;
  const int s = v0 + v1 + v2 + v3;
  const int lane = t & 63, w = t >> 6;
  int x = s;
#pragma unroll
  for (int off = 1; off < 64; off <<= 1) {
    int y = __shfl_up(x, off);
    if (lane >= off) x += y;
  }
  __shared__ int ws[4];
  if (lane == 63) ws[w] = x;
  __syncthreads();
  int woff = 0;
  for (int i = 0; i < w; ++i) woff += ws[i];
  int run = woff + x - s;
  if (base + 0 < n) { pexcl[base + 0] = run; run += v0; }
  if (base + 1 < n) { pexcl[base + 1] = run; run += v1; }
  if (base + 2 < n) { pexcl[base + 2] = run; run += v2; }
  if (base + 3 < n) { pexcl[base + 3] = run; run += v3; }
  if (t == 0) bsum[blockIdx.x] = ws[0] + ws[1] + ws[2] + ws[3];
}

__global__ __launch_bounds__(256) void k_scan2(
    const int* __restrict__ bsum, int* __restrict__ boff, int B) {
  const int t = threadIdx.x;
  const int s = t < B ? bsum[t] : 0;
  const int lane = t & 63, w = t >> 6;
  int x = s;
#pragma unroll
  for (int off = 1; off < 64; off <<= 1) {
    int y = __shfl_up(x, off);
    if (lane >= off) x += y;
  }
  __shared__ int ws[4];
  if (lane == 63) ws[w] = x;
  __syncthreads();
  int woff = 0;
  for (int i = 0; i < w; ++i) woff += ws[i];
  if (t < B) boff[t] = woff + x - s;
}

__global__ __launch_bounds__(256) void k_scan3(
    const int* __restrict__ pexcl, const int* __restrict__ boff,
    int* __restrict__ offsets, int n, int ne) {
  const int i = blockIdx.x * 256 + threadIdx.x;
  if (i < n) offsets[i] = pexcl[i] + boff[i >> 10];
  if (i == 0) offsets[n] = ne;
}

// ------ Kernel S: scatter src into dst-CSR (atomic-free, 4 edges/thread) ---
__global__ __launch_bounds__(256) void k_scatter(
    const int* __restrict__ src, const int* __restrict__ dst,
    const int* __restrict__ rank, const int* __restrict__ offsets,
    int* __restrict__ src_sorted, int ne) {
  const int e4 = (blockIdx.x * 256 + threadIdx.x) * 4;
  if (e4 + 4 <= ne) {
    const int4 s = *(const int4*)(src + e4);
    const int4 d = *(const int4*)(dst + e4);
    const int4 r = *(const int4*)(rank + e4);
    src_sorted[offsets[d.x] + r.x] = s.x;
    src_sorted[offsets[d.y] + r.y] = s.y;
    src_sorted[offsets[d.z] + r.z] = s.z;
    src_sorted[offsets[d.w] + r.w] = s.w;
  } else {
    for (int e = e4; e < ne; ++e)
      src_sorted[offsets[dst[e]] + rank[e]] = src[e];
  }
}

// ------ Kernel D: fused softmax + aggregation, one wave per dst node -------
__global__ __launch_bounds__(256) void k_aggr(
    const int* __restrict__ offsets, const int* __restrict__ src_sorted,
    const float* __restrict__ el, const float* __restrict__ er,
    const unsigned* __restrict__ ftb2, float* __restrict__ out, int n) {
  const int wid = (blockIdx.x * 256 + threadIdx.x) >> 6;
  if (wid >= n) return;
  const int lane = threadIdx.x & 63;
  const int hsel = lane >> 5;  // head of elem 'lane'; elem lane+64 -> 2+hsel
  const int start = offsets[wid], end = offsets[wid + 1];
  const float er0 = er[wid * NH + hsel];
  const float er1 = er[wid * NH + 2 + hsel];
  float acc0 = 0.f, acc1 = 0.f, den0 = 0.f, den1 = 0.f;

  int i = start;
  for (; i + 2 <= end; i += 2) {
    const int sA = src_sorted[i], sB = src_sorted[i + 1];
    float eA0 = el[sA * NH + hsel] + er0;
    float eA1 = el[sA * NH + 2 + hsel] + er1;
    float eB0 = el[sB * NH + hsel] + er0;
    float eB1 = el[sB * NH + 2 + hsel] + er1;
    eA0 = eA0 > 0.f ? eA0 : NEG_SLOPE * eA0;
    eA1 = eA1 > 0.f ? eA1 : NEG_SLOPE * eA1;
    eB0 = eB0 > 0.f ? eB0 : NEG_SLOPE * eB0;
    eB1 = eB1 > 0.f ? eB1 : NEG_SLOPE * eB1;
    const float pA0 = __expf(eA0), pA1 = __expf(eA1);
    const float pB0 = __expf(eB0), pB1 = __expf(eB1);
    const unsigned vA = ftb2[(size_t)sA * 64 + lane];
    const unsigned vB = ftb2[(size_t)sB * 64 + lane];
    const float fA0 = __uint_as_float(vA << 16);
    const float fA1 = __uint_as_float(vA & 0xFFFF0000u);
    const float fB0 = __uint_as_float(vB << 16);
    const float fB1 = __uint_as_float(vB & 0xFFFF0000u);
    acc0 += fA0 * pA0 + fB0 * pB0;
    acc1 += fA1 * pA1 + fB1 * pB1;
    den0 += pA0 + pB0;
    den1 += pA1 + pB1;
  }
  if (i < end) {
    const int s = src_sorted[i];
    float e0 = el[s * NH + hsel] + er0;
    float e1 = el[s * NH + 2 + hsel] + er1;
    e0 = e0 > 0.f ? e0 : NEG_SLOPE * e0;
    e1 = e1 > 0.f ? e1 : NEG_SLOPE * e1;
    const float p0 = __expf(e0), p1 = __expf(e1);
    const unsigned v = ftb2[(size_t)s * 64 + lane];
    acc0 += __uint_as_float(v << 16) * p0;
    acc1 += __uint_as_float(v & 0xFFFF0000u) * p1;
    den0 += p0;
    den1 += p1;
  }
  den0 = den0 > 0.f ? den0 : 1.f;  // isolated-node guard (matches reference)
  den1 = den1 > 0.f ? den1 : 1.f;
  float* orow = out + (size_t)wid * HD;
  orow[lane] = acc0 / den0;
  orow[64 + lane] = acc1 / den1;
}

extern "C" void kernel_launch(void* const* d_in, const int* in_sizes, int n_in,
                              void* d_out, int out_size, void* d_ws, size_t ws_size,
                              hipStream_t stream) {
  const float* feat   = (const float*)d_in[0];
  const float* W      = (const float*)d_in[1];
  const float* attn_l = (const float*)d_in[2];
  const float* attn_r = (const float*)d_in[3];
  const int*   src    = (const int*)d_in[4];
  const int*   dst    = (const int*)d_in[5];
  const int n  = in_sizes[0] / IN_F;
  const int ne = in_sizes[4];
  float* out = (float*)d_out;

  // workspace layout (16B-aligned blocks first)
  char* wp = (char*)d_ws;
  unsigned* ftb2    = (unsigned*)wp; wp += (size_t)n * 64 * 4;   // 25.6 MB
  float* el         = (float*)wp;    wp += (size_t)n * NH * 4;
  float* er         = (float*)wp;    wp += (size_t)n * NH * 4;
  int*   rank       = (int*)wp;      wp += (size_t)ne * 4;
  int*   src_sorted = (int*)wp;      wp += (size_t)ne * 4;
  int*   deg        = (int*)wp;      wp += (size_t)n * 4;
  int*   pexcl      = (int*)wp;      wp += (size_t)n * 4;
  int*   offsets    = (int*)wp;      wp += (size_t)(n + 1) * 4;
  int*   bsum       = (int*)wp;      wp += 256 * 4;
  int*   boff       = (int*)wp;      wp += 256 * 4;

  hipMemsetAsync(deg, 0, (size_t)n * 4, stream);

  const int B = (n + 1023) / 1024;
  k_gemm<<<(n + 127) / 128, 256, 0, stream>>>(feat, W, attn_l, attn_r, ftb2, el, er, n);
  k_rank<<<(ne + 1023) / 1024, 256, 0, stream>>>(dst, deg, rank, ne);
  k_scan1<<<B, 256, 0, stream>>>(deg, pexcl, bsum, n);
  k_scan2<<<1, 256, 0, stream>>>(bsum, boff, B);
  k_scan3<<<(n + 255) / 256, 256, 0, stream>>>(pexcl, boff, offsets, n, ne);
  k_scatter<<<(ne + 1023) / 1024, 256, 0, stream>>>(src, dst, rank, offsets,
                                                    src_sorted, ne);
  k_aggr<<<(n + 3) / 4, 256, 0, stream>>>(offsets, src_sorted, el, er, ftb2, out, n);
}